// Round 17
// baseline (127.089 us; speedup 1.0000x reference)
//
#include <hip/hip_runtime.h>
#include <stdint.h>

#define D_MODEL 1024
#define NHEADS  16
#define DEPTH   64
#define BATCH   2
#define SEQ     2048
#define M_TOK   (BATCH*SEQ)   // 4096

typedef __attribute__((ext_vector_type(8)))  short short8;
typedef __attribute__((ext_vector_type(4)))  float f32x4;
typedef __attribute__((ext_vector_type(16))) float f32x16;
typedef __attribute__((ext_vector_type(4)))  unsigned int uint4v;

#if defined(__has_builtin)
#if __has_builtin(__builtin_amdgcn_exp2f)
#define EXP2(x) __builtin_amdgcn_exp2f(x)
#endif
#endif
#ifndef EXP2
#define EXP2(x) exp2f(x)
#endif

__device__ __forceinline__ unsigned short f2bf(float f) {
  unsigned int u = __float_as_uint(f);
  u += 0x7fffu + ((u >> 16) & 1u);
  return (unsigned short)(u >> 16);
}

__device__ __forceinline__ unsigned int cvt_pk_bf16(float lo, float hi) {
  unsigned int r;
  asm("v_cvt_pk_bf16_f32 %0, %1, %2" : "=v"(r) : "v"(lo), "v"(hi));
  return r;
}

__device__ __forceinline__ void gload_lds16(const unsigned short* g, unsigned short* l) {
  __builtin_amdgcn_global_load_lds((const __attribute__((address_space(1))) void*)g,
                                   (__attribute__((address_space(3))) void*)l, 16, 0, 0);
}

// ------------- merged prep: x->bf16 | Wqkv permute-transpose | Wproj transpose -------------
__global__ void mha_prep(const float* __restrict__ x, const float* __restrict__ Wqkv,
                         const float* __restrict__ Wproj,
                         unsigned short* __restrict__ xb,
                         unsigned short* __restrict__ wqkT,
                         unsigned short* __restrict__ wvT,
                         unsigned short* __restrict__ wpT) {
  __shared__ float tile[32][33];
  int id = blockIdx.x, t = threadIdx.x;
  if (id < 2048) {
    int i = (id * 256 + t) * 8;
    float4 a = *(const float4*)(x + i);
    float4 b = *(const float4*)(x + i + 4);
    uint4 r;
    r.x = (unsigned)f2bf(a.x) | ((unsigned)f2bf(a.y) << 16);
    r.y = (unsigned)f2bf(a.z) | ((unsigned)f2bf(a.w) << 16);
    r.z = (unsigned)f2bf(b.x) | ((unsigned)f2bf(b.y) << 16);
    r.w = (unsigned)f2bf(b.z) | ((unsigned)f2bf(b.w) << 16);
    *(uint4*)(xb + i) = r;
  } else if (id < 5120) {
    int b = id - 2048;
    int c0 = (b % 96) * 32, k0 = (b / 96) * 32;
    int tx = t & 31, ty = t >> 5;
    for (int i = ty; i < 32; i += 8)
      tile[i][tx] = Wqkv[(size_t)(k0 + i) * 3072 + c0 + tx];
    __syncthreads();
    for (int i = ty; i < 32; i += 8) {
      int c = c0 + i;
      int hd = c / 3;
      int s = c - hd * 3;
      unsigned short v = f2bf(tile[tx][i]);
      if (s < 2) wqkT[(size_t)(s * 1024 + hd) * 1024 + k0 + tx] = v;
      else       wvT [(size_t)hd * 1024 + k0 + tx] = v;
    }
  } else {
    int b = id - 5120;
    int c0 = (b & 31) * 32, k0 = (b >> 5) * 32;
    int tx = t & 31, ty = t >> 5;
    for (int i = ty; i < 32; i += 8)
      tile[i][tx] = Wproj[(size_t)(k0 + i) * 1024 + c0 + tx];
    __syncthreads();
    for (int i = ty; i < 32; i += 8)
      wpT[(size_t)(c0 + i) * 1024 + k0 + tx] = f2bf(tile[tx][i]);
  }
}

// ------------- merged QKV gemm: 2-phase double-buffer (T3-minimum), BK=64, swizzled -------------
// Phase recipe per catalog: STAGE(t+1) issued BEFORE compute(t); ONE vmcnt(0)+barrier
// per K-step (waits on loads issued a full compute-phase earlier). LDS 2x32KB = 64KB
// -> 2 blocks/CU (trade 3->2 blocks for explicit prefetch overlap).
__global__ __launch_bounds__(256, 2) void mha_gemm_qkv(
    const unsigned short* __restrict__ xb,
    const unsigned short* __restrict__ wqkT,
    const unsigned short* __restrict__ wvT,
    const float* __restrict__ bias,
    unsigned short* __restrict__ Qb,
    unsigned short* __restrict__ Kb,
    unsigned short* __restrict__ Vtb)
{
  __shared__ __align__(16) unsigned short As[2 * 128 * 64];   // 32KB
  __shared__ __align__(16) unsigned short Bs[2 * 128 * 64];   // 32KB
  const int K = 1024;
  int id = blockIdx.x;
  bool m0 = id < 512;
  int bx, by, bz = 0;
  const unsigned short *A, *Bt;
  if (m0) {
    int xcd = id & 7, idx = id >> 3;
    by = xcd * 4 + (idx >> 4);     // 4 A-stripes per XCD
    bx = idx & 15;
    A = xb; Bt = wqkT;
  } else {
    int b2 = id - 512;
    bx = b2 & 15; by = (b2 >> 4) & 7; bz = b2 >> 7;
    A = wvT; Bt = xb + (size_t)bz * SEQ * D_MODEL;
  }
  int t = threadIdx.x;
  int wv = t >> 6, lane = t & 63;
  int l15 = lane & 15, l4 = lane >> 4;
  int wr = wv >> 1, wc = wv & 1;
  int blkM = by * 128, blkN = bx * 128;

  f32x4 acc[4][4];
  for (int m = 0; m < 4; m++) for (int n = 0; n < 4; n++) acc[m][n] = (f32x4){0.f,0.f,0.f,0.f};

#define GSTAGE(BUF, KT)                                                                 \
  do {                                                                                  \
    _Pragma("unroll") for (int i = 0; i < 4; i++) {                                     \
      int e = i * 256 + t;                                                              \
      int row = e >> 3;                                                                 \
      int sc = ((e & 7) ^ (row & 7)) * 8;                                               \
      gload_lds16(A  + (size_t)(blkM + row) * K + (KT) + sc, As + (BUF) * 8192 + e * 8);\
      gload_lds16(Bt + (size_t)(blkN + row) * K + (KT) + sc, Bs + (BUF) * 8192 + e * 8);\
    }                                                                                   \
  } while (0)

#define GBODY(BUF, KT)                                                                  \
  do {                                                                                  \
    if ((KT) + 64 < K) GSTAGE((BUF) ^ 1, (KT) + 64);                                    \
    _Pragma("unroll") for (int kk = 0; kk < 2; kk++) {                                  \
      int gp = ((kk * 4 + l4) ^ (l15 & 7)) * 8;                                         \
      short8 af[4], bf[4];                                                              \
      _Pragma("unroll") for (int m = 0; m < 4; m++)                                     \
        af[m] = *(const short8*)&As[(BUF) * 8192 + (wr * 64 + m * 16 + l15) * 64 + gp]; \
      _Pragma("unroll") for (int n = 0; n < 4; n++)                                     \
        bf[n] = *(const short8*)&Bs[(BUF) * 8192 + (wc * 64 + n * 16 + l15) * 64 + gp]; \
      __builtin_amdgcn_s_setprio(1);                                                    \
      _Pragma("unroll") for (int m = 0; m < 4; m++)                                     \
        _Pragma("unroll") for (int n = 0; n < 4; n++)                                   \
          acc[m][n] = __builtin_amdgcn_mfma_f32_16x16x32_bf16(af[m], bf[n], acc[m][n], 0, 0, 0); \
      __builtin_amdgcn_s_setprio(0);                                                    \
    }                                                                                   \
    asm volatile("s_waitcnt vmcnt(0)" ::: "memory");                                    \
    __builtin_amdgcn_sched_barrier(0);                                                  \
    __builtin_amdgcn_s_barrier();                                                       \
    __builtin_amdgcn_sched_barrier(0);                                                  \
  } while (0)

  GSTAGE(0, 0);
  asm volatile("s_waitcnt vmcnt(0)" ::: "memory");
  __builtin_amdgcn_sched_barrier(0);
  __builtin_amdgcn_s_barrier();
  __builtin_amdgcn_sched_barrier(0);

  for (int kt = 0; kt < K; kt += 128) {
    GBODY(0, kt);
    GBODY(1, kt + 64);
  }
#undef GSTAGE
#undef GBODY

  int row0 = blkM + wr * 64;
  int col0 = blkN + wc * 64;
  #pragma unroll
  for (int m = 0; m < 4; m++) {
    #pragma unroll
    for (int n = 0; n < 4; n++) {
      int colb = col0 + n * 16 + l15;
      #pragma unroll
      for (int j = 0; j < 4; j++) {
        int row = row0 + m * 16 + l4 * 4 + j;
        float v = acc[m][n][j];
        if (m0) {
          int s = colb >> 10, hd = colb & 1023;
          v += bias[hd * 3 + s];
          if (s == 0) v *= 0.18033688011112042f;  // (1/8)*log2(e): softmax scale + exp2 base
          size_t idx = ((size_t)((row >> 11) * NHEADS + (hd >> 6)) * SEQ + (row & 2047)) * DEPTH + (hd & 63);
          (s == 0 ? Qb : Kb)[idx] = f2bf(v);
        } else {
          v += bias[row * 3 + 2];
          Vtb[((size_t)(bz * 1024 + row)) * SEQ + colb] = f2bf(v);
        }
      }
    }
  }
}

// ---------------- proj gemm: 2-phase double-buffer, 128x64 tiles, BK=64, swizzled ----------------
// LDS 2x24KB = 48KB -> keeps 3 blocks/CU.
__global__ __launch_bounds__(256, 3) void mha_gemm_proj(
    const unsigned short* __restrict__ A,
    const unsigned short* __restrict__ Bt,
    const float* __restrict__ bias,
    float* __restrict__ out_f)
{
  __shared__ __align__(16) unsigned short As[2 * 128 * 64];   // 32KB
  __shared__ __align__(16) unsigned short Bs[2 * 64 * 64];    // 16KB
  const int K = 1024;
  int id = blockIdx.x;                 // 512 blocks
  int xcd = id & 7, idx = id >> 3;
  int by = xcd * 4 + (idx >> 4);       // 0..31
  int bx = idx & 15;                   // 0..15 (64-col panels)
  int t = threadIdx.x;
  int wv = t >> 6, lane = t & 63;
  int l15 = lane & 15, l4 = lane >> 4;
  int wr = wv >> 1, wc = wv & 1;
  int blkM = by * 128, blkN = bx * 64;

  f32x4 acc[4][2];
  for (int m = 0; m < 4; m++) for (int n = 0; n < 2; n++) acc[m][n] = (f32x4){0.f,0.f,0.f,0.f};

#define PSTAGE(BUF, KT)                                                                 \
  do {                                                                                  \
    _Pragma("unroll") for (int i = 0; i < 4; i++) {                                     \
      int e = i * 256 + t;                                                              \
      int row = e >> 3;                                                                 \
      int sc = ((e & 7) ^ (row & 7)) * 8;                                               \
      gload_lds16(A + (size_t)(blkM + row) * K + (KT) + sc, As + (BUF) * 8192 + e * 8); \
    }                                                                                   \
    _Pragma("unroll") for (int i = 0; i < 2; i++) {                                     \
      int e = i * 256 + t;                                                              \
      int row = e >> 3;                                                                 \
      int sc = ((e & 7) ^ (row & 7)) * 8;                                               \
      gload_lds16(Bt + (size_t)(blkN + row) * K + (KT) + sc, Bs + (BUF) * 4096 + e * 8);\
    }                                                                                   \
  } while (0)

#define PBODY(BUF, KT)                                                                  \
  do {                                                                                  \
    if ((KT) + 64 < K) PSTAGE((BUF) ^ 1, (KT) + 64);                                    \
    _Pragma("unroll") for (int kk = 0; kk < 2; kk++) {                                  \
      int gp = ((kk * 4 + l4) ^ (l15 & 7)) * 8;                                         \
      short8 af[4], bf[2];                                                              \
      _Pragma("unroll") for (int m = 0; m < 4; m++)                                     \
        af[m] = *(const short8*)&As[(BUF) * 8192 + (wr * 64 + m * 16 + l15) * 64 + gp]; \
      _Pragma("unroll") for (int n = 0; n < 2; n++)                                     \
        bf[n] = *(const short8*)&Bs[(BUF) * 4096 + (wc * 32 + n * 16 + l15) * 64 + gp]; \
      __builtin_amdgcn_s_setprio(1);                                                    \
      _Pragma("unroll") for (int m = 0; m < 4; m++)                                     \
        _Pragma("unroll") for (int n = 0; n < 2; n++)                                   \
          acc[m][n] = __builtin_amdgcn_mfma_f32_16x16x32_bf16(af[m], bf[n], acc[m][n], 0, 0, 0); \
      __builtin_amdgcn_s_setprio(0);                                                    \
    }                                                                                   \
    asm volatile("s_waitcnt vmcnt(0)" ::: "memory");                                    \
    __builtin_amdgcn_sched_barrier(0);                                                  \
    __builtin_amdgcn_s_barrier();                                                       \
    __builtin_amdgcn_sched_barrier(0);                                                  \
  } while (0)

  PSTAGE(0, 0);
  asm volatile("s_waitcnt vmcnt(0)" ::: "memory");
  __builtin_amdgcn_sched_barrier(0);
  __builtin_amdgcn_s_barrier();
  __builtin_amdgcn_sched_barrier(0);

  for (int kt = 0; kt < K; kt += 128) {
    PBODY(0, kt);
    PBODY(1, kt + 64);
  }
#undef PSTAGE
#undef PBODY

  int row0 = blkM + wr * 64;
  int col0 = blkN + wc * 32;
  #pragma unroll
  for (int m = 0; m < 4; m++) {
    #pragma unroll
    for (int n = 0; n < 2; n++) {
      int colb = col0 + n * 16 + l15;
      #pragma unroll
      for (int j = 0; j < 4; j++) {
        int row = row0 + m * 16 + l4 * 4 + j;
        out_f[(size_t)row * D_MODEL + colb] = acc[m][n][j] + bias[colb];
      }
    }
  }
}

// -------- flash attention: r15 (best, 45.6us ~ structure ceiling ~943 TF; frozen) --------
__global__ __launch_bounds__(512, 2) void mha_attn(
    const unsigned short* __restrict__ Q,
    const unsigned short* __restrict__ Kb,
    const unsigned short* __restrict__ Vt,
    unsigned short* __restrict__ O)
{
  const int N = SEQ;
  const int NIT = N / 64;                    // 32
  int id = blockIdx.x;                       // 512 blocks
  int bh    = (id & 7) * 4 + ((id >> 7) & 3);  // 4 heads per XCD
  int qtile = (id >> 3) & 15;                // 16 q-tiles of 128 rows
  int t = threadIdx.x, wv = t >> 6, lane = t & 63;
  int l31 = lane & 31, hi = lane >> 5;
  int kh = wv & 1, qh = wv >> 1;             // key-half, q-group 0..3

  __shared__ __align__(16) unsigned short SMEM[3 * 8192];  // 48KB: per buf {K[4096]|V[4096]}

  const unsigned short* Kbh = Kb + (size_t)bh * N * DEPTH;
  const unsigned short* Vbh = Vt + (size_t)bh * DEPTH * N;

  int qrow = qtile * 128 + qh * 32 + l31;
  const unsigned short* Qp = Q + ((size_t)bh * N + qrow) * DEPTH + hi * 8;
  short8 qf[4];
  #pragma unroll
  for (int c = 0; c < 4; c++) qf[c] = *(const short8*)(Qp + c * 16);

  int srow = t >> 3;                         // 0..63
  int sc8  = ((t & 7) ^ (srow & 7)) * 8;     // pre-swizzled source column
  const unsigned short* kst = Kbh + (size_t)srow * DEPTH + sc8;
  const unsigned short* vst = Vbh + (size_t)srow * N + sc8;

  int rbK = (kh * 32 + l31) * 64;
  int rbV0 = l31 * 64, rbV1 = rbV0 + 2048;
  int goQK[4], goPV[2];
  #pragma unroll
  for (int c = 0; c < 4; c++) goQK[c] = ((c * 2 + hi) ^ (l31 & 7)) * 8;
  #pragma unroll
  for (int lc = 0; lc < 2; lc++) goPV[lc] = ((kh * 4 + lc * 2 + hi) ^ (l31 & 7)) * 8;

  short8 ones;
  #pragma unroll
  for (int i = 0; i < 8; i++) ones[i] = (short)0x3F80;   // bf16 1.0

  f32x16 o0, o1, lsacc, zc;
  #pragma unroll
  for (int i = 0; i < 16; i++) { o0[i] = 0.f; o1[i] = 0.f; lsacc[i] = 0.f; zc[i] = 0.f; }

#define STAGE(buf, kt)                                                                  \
  do {                                                                                  \
    unsigned short* base = SMEM + (buf) * 8192;                                         \
    gload_lds16(kst + (size_t)(kt) * DEPTH, base + t * 8);                              \
    gload_lds16(vst + (kt),                 base + 4096 + t * 8);                       \
  } while (0)

  STAGE(0, 0);
  STAGE(1, 64);
  asm volatile("s_waitcnt vmcnt(2)" ::: "memory");
  __builtin_amdgcn_sched_barrier(0);
  __builtin_amdgcn_s_barrier();
  __builtin_amdgcn_sched_barrier(0);

  int cur = 0, sb = 2;                       // compute buf, stage-target buf
  for (int it = 0; it < NIT; ++it) {
    if (it + 2 < NIT) STAGE(sb, (it + 2) * 64);
    {
      const unsigned short* Kc = SMEM + cur * 8192;
      const unsigned short* Vc = Kc + 4096;
      __builtin_amdgcn_s_setprio(1);
      short8 ka0 = *(const short8*)&Kc[rbK + goQK[0]];
      f32x16 s = __builtin_amdgcn_mfma_f32_32x32x16_bf16(ka0, qf[0], zc, 0, 0, 0);
      #pragma unroll
      for (int c = 1; c < 4; c++) {
        short8 ka = *(const short8*)&Kc[rbK + goQK[c]];
        s = __builtin_amdgcn_mfma_f32_32x32x16_bf16(ka, qf[c], s, 0, 0, 0);
      }
      __builtin_amdgcn_s_setprio(0);
      float p[16];
      #pragma unroll
      for (int r = 0; r < 16; r++) p[r] = EXP2(s[r]);
      #pragma unroll
      for (int lc = 0; lc < 2; lc++) {
        unsigned int X0 = cvt_pk_bf16(p[8*lc+0], p[8*lc+1]);
        unsigned int X1 = cvt_pk_bf16(p[8*lc+2], p[8*lc+3]);
        unsigned int X2 = cvt_pk_bf16(p[8*lc+4], p[8*lc+5]);
        unsigned int X3 = cvt_pk_bf16(p[8*lc+6], p[8*lc+7]);
        auto r02 = __builtin_amdgcn_permlane32_swap(X0, X2, false, false);
        auto r13 = __builtin_amdgcn_permlane32_swap(X1, X3, false, false);
        uint4v wvec; wvec[0] = r02[0]; wvec[1] = r13[0]; wvec[2] = r02[1]; wvec[3] = r13[1];
        short8 bfrag = __builtin_bit_cast(short8, wvec);
        short8 va = *(const short8*)&Vc[rbV0 + goPV[lc]];
        short8 vb = *(const short8*)&Vc[rbV1 + goPV[lc]];
        __builtin_amdgcn_s_setprio(1);
        o0 = __builtin_amdgcn_mfma_f32_32x32x16_bf16(va, bfrag, o0, 0, 0, 0);
        o1 = __builtin_amdgcn_mfma_f32_32x32x16_bf16(vb, bfrag, o1, 0, 0, 0);
        lsacc = __builtin_amdgcn_mfma_f32_32x32x16_bf16(ones, bfrag, lsacc, 0, 0, 0);
        __builtin_amdgcn_s_setprio(0);
      }
    }
    if (it < NIT - 1) {
      if (it + 2 < NIT) asm volatile("s_waitcnt vmcnt(2)" ::: "memory");
      else              asm volatile("s_waitcnt vmcnt(0)" ::: "memory");
      __builtin_amdgcn_sched_barrier(0);
      __builtin_amdgcn_s_barrier();
      __builtin_amdgcn_sched_barrier(0);
    }
    cur = (cur == 2) ? 0 : cur + 1;
    sb  = (sb  == 2) ? 0 : sb  + 1;
  }
#undef STAGE

  float ls = lsacc[0];   // every acc reg = sum over this wave's key-half (all tiles)

  __syncthreads();                                 // everyone done reading K/V tiles
  float* cmb = (float*)SMEM;                       // 4 slots x 64 x 33 = 33.8KB <= 48KB
  if (kh == 1) {
    float* c0 = cmb + (qh * 64 + lane) * 33;
    #pragma unroll
    for (int i = 0; i < 16; i++) { c0[i] = o0[i]; c0[16 + i] = o1[i]; }
    c0[32] = ls;
  }
  __syncthreads();
  if (kh == 0) {
    const float* c0 = cmb + (qh * 64 + lane) * 33;
    #pragma unroll
    for (int i = 0; i < 16; i++) { o0[i] += c0[i]; o1[i] += c0[16 + i]; }
    float rl = 1.0f / (ls + c0[32]);

    int b = bh >> 4, h = bh & 15;
    unsigned short* Op = O + ((size_t)b * N + qrow) * D_MODEL + h * DEPTH;
    #pragma unroll
    for (int gq = 0; gq < 4; gq++) {
      #pragma unroll
      for (int rp = 0; rp < 2; rp++) {
        int reg = gq * 4 + rp * 2;
        int d = gq * 8 + hi * 4 + rp * 2;
        *(unsigned int*)(Op + d)      = cvt_pk_bf16(o0[reg] * rl, o0[reg + 1] * rl);
        *(unsigned int*)(Op + 32 + d) = cvt_pk_bf16(o1[reg] * rl, o1[reg + 1] * rl);
      }
    }
  }
}

extern "C" void kernel_launch(void* const* d_in, const int* in_sizes, int n_in,
                              void* d_out, int out_size, void* d_ws, size_t ws_size,
                              hipStream_t stream) {
  const float* x     = (const float*)d_in[0];
  const float* Wqkv  = (const float*)d_in[1];
  const float* bqkv  = (const float*)d_in[2];
  const float* Wproj = (const float*)d_in[3];
  const float* bproj = (const float*)d_in[4];
  float* out = (float*)d_out;

  char* w = (char*)d_ws;
  unsigned short* xb    = (unsigned short*)(w);                       // 8 MB
  unsigned short* wqkT  = (unsigned short*)(w + 8388608);             // 4 MB
  unsigned short* wvT   = (unsigned short*)(w + 8388608 + 4194304);   // 2 MB
  unsigned short* wpT   = (unsigned short*)(w + 8388608 + 4194304 + 2097152);  // 2 MB
  unsigned short* Qbuf  = (unsigned short*)(w + 16777216);            // 8 MB
  unsigned short* Kbuf  = (unsigned short*)(w + 16777216 + 8388608);  // 8 MB
  unsigned short* Vtb   = (unsigned short*)(w + 16777216 + 16777216); // 8 MB
  unsigned short* AOut  = (unsigned short*)(w + 16777216 + 25165824); // 8 MB

  // 1. merged prep (x cvt + Wqkv permute + Wproj transpose)
  mha_prep<<<6144, 256, 0, stream>>>(x, Wqkv, Wproj, xb, wqkT, wvT, wpT);
  // 2. merged QKV gemm (QK: 512 blocks XCD-mapped, V: 256 blocks), 2-phase dbuf BK=64
  mha_gemm_qkv<<<768, 256, 0, stream>>>(xb, wqkT, wvT, bqkv, Qbuf, Kbuf, Vtb);
  // 3. flash attention (r15 frozen: 512 x 512, triple-buffer counted vmcnt)
  mha_attn<<<512, 512, 0, stream>>>(Qbuf, Kbuf, Vtb, AOut);
  // 4. projection gemm 128x64 tiles, 2-phase dbuf -> fp32 out
  mha_gemm_proj<<<512, 256, 0, stream>>>(AOut, wpT, bproj, out);
}

// Round 18
// 110.704 us; speedup vs baseline: 1.1480x; 1.1480x over previous
//
#include <hip/hip_runtime.h>
#include <stdint.h>

#define D_MODEL 1024
#define NHEADS  16
#define DEPTH   64
#define BATCH   2
#define SEQ     2048
#define M_TOK   (BATCH*SEQ)   // 4096

typedef __attribute__((ext_vector_type(8)))  short short8;
typedef __attribute__((ext_vector_type(4)))  float f32x4;
typedef __attribute__((ext_vector_type(16))) float f32x16;
typedef __attribute__((ext_vector_type(4)))  unsigned int uint4v;

#if defined(__has_builtin)
#if __has_builtin(__builtin_amdgcn_exp2f)
#define EXP2(x) __builtin_amdgcn_exp2f(x)
#endif
#endif
#ifndef EXP2
#define EXP2(x) exp2f(x)
#endif

__device__ __forceinline__ unsigned short f2bf(float f) {
  unsigned int u = __float_as_uint(f);
  u += 0x7fffu + ((u >> 16) & 1u);
  return (unsigned short)(u >> 16);
}

__device__ __forceinline__ unsigned int cvt_pk_bf16(float lo, float hi) {
  unsigned int r;
  asm("v_cvt_pk_bf16_f32 %0, %1, %2" : "=v"(r) : "v"(lo), "v"(hi));
  return r;
}

__device__ __forceinline__ void gload_lds16(const unsigned short* g, unsigned short* l) {
  __builtin_amdgcn_global_load_lds((const __attribute__((address_space(1))) void*)g,
                                   (__attribute__((address_space(3))) void*)l, 16, 0, 0);
}

// ------------- merged prep: x->bf16 | Wqkv permute-transpose | Wproj transpose -------------
__global__ void mha_prep(const float* __restrict__ x, const float* __restrict__ Wqkv,
                         const float* __restrict__ Wproj,
                         unsigned short* __restrict__ xb,
                         unsigned short* __restrict__ wqkT,
                         unsigned short* __restrict__ wvT,
                         unsigned short* __restrict__ wpT) {
  __shared__ float tile[32][33];
  int id = blockIdx.x, t = threadIdx.x;
  if (id < 2048) {
    int i = (id * 256 + t) * 8;
    float4 a = *(const float4*)(x + i);
    float4 b = *(const float4*)(x + i + 4);
    uint4 r;
    r.x = (unsigned)f2bf(a.x) | ((unsigned)f2bf(a.y) << 16);
    r.y = (unsigned)f2bf(a.z) | ((unsigned)f2bf(a.w) << 16);
    r.z = (unsigned)f2bf(b.x) | ((unsigned)f2bf(b.y) << 16);
    r.w = (unsigned)f2bf(b.z) | ((unsigned)f2bf(b.w) << 16);
    *(uint4*)(xb + i) = r;
  } else if (id < 5120) {
    int b = id - 2048;
    int c0 = (b % 96) * 32, k0 = (b / 96) * 32;
    int tx = t & 31, ty = t >> 5;
    for (int i = ty; i < 32; i += 8)
      tile[i][tx] = Wqkv[(size_t)(k0 + i) * 3072 + c0 + tx];
    __syncthreads();
    for (int i = ty; i < 32; i += 8) {
      int c = c0 + i;
      int hd = c / 3;
      int s = c - hd * 3;
      unsigned short v = f2bf(tile[tx][i]);
      if (s < 2) wqkT[(size_t)(s * 1024 + hd) * 1024 + k0 + tx] = v;
      else       wvT [(size_t)hd * 1024 + k0 + tx] = v;
    }
  } else {
    int b = id - 5120;
    int c0 = (b & 31) * 32, k0 = (b >> 5) * 32;
    int tx = t & 31, ty = t >> 5;
    for (int i = ty; i < 32; i += 8)
      tile[i][tx] = Wproj[(size_t)(k0 + i) * 1024 + c0 + tx];
    __syncthreads();
    for (int i = ty; i < 32; i += 8)
      wpT[(size_t)(c0 + i) * 1024 + k0 + tx] = f2bf(tile[tx][i]);
  }
}

// ------------- merged QKV gemm, BK=64 + XOR-swizzled LDS + XCD-mapped QK blocks -------------
__global__ __launch_bounds__(256, 3) void mha_gemm_qkv(
    const unsigned short* __restrict__ xb,
    const unsigned short* __restrict__ wqkT,
    const unsigned short* __restrict__ wvT,
    const float* __restrict__ bias,
    unsigned short* __restrict__ Qb,
    unsigned short* __restrict__ Kb,
    unsigned short* __restrict__ Vtb)
{
  __shared__ __align__(16) unsigned short As[128 * 64];   // 16KB
  __shared__ __align__(16) unsigned short Bs[128 * 64];   // 16KB
  const int K = 1024;
  int id = blockIdx.x;
  bool m0 = id < 512;
  int bx, by, bz = 0;
  const unsigned short *A, *Bt;
  if (m0) {
    int xcd = id & 7, idx = id >> 3;
    by = xcd * 4 + (idx >> 4);     // 4 A-stripes per XCD
    bx = idx & 15;
    A = xb; Bt = wqkT;
  } else {
    int b2 = id - 512;
    bx = b2 & 15; by = (b2 >> 4) & 7; bz = b2 >> 7;
    A = wvT; Bt = xb + (size_t)bz * SEQ * D_MODEL;
  }
  int t = threadIdx.x;
  int wv = t >> 6, lane = t & 63;
  int l15 = lane & 15, l4 = lane >> 4;
  int wr = wv >> 1, wc = wv & 1;
  int blkM = by * 128, blkN = bx * 128;

  f32x4 acc[4][4];
  for (int m = 0; m < 4; m++) for (int n = 0; n < 4; n++) acc[m][n] = (f32x4){0.f,0.f,0.f,0.f};

  for (int kt = 0; kt < K; kt += 64) {
    #pragma unroll
    for (int i = 0; i < 4; i++) {
      int e = i * 256 + t;
      int row = e >> 3;
      int sc = ((e & 7) ^ (row & 7)) * 8;   // pre-swizzled source granule
      gload_lds16(A  + (size_t)(blkM + row) * K + kt + sc, As + e * 8);
      gload_lds16(Bt + (size_t)(blkN + row) * K + kt + sc, Bs + e * 8);
    }
    __syncthreads();
    #pragma unroll
    for (int kk = 0; kk < 2; kk++) {
      int gp = ((kk * 4 + l4) ^ (l15 & 7)) * 8;   // swizzled read slot (row&7 == l15&7)
      short8 af[4], bf[4];
      #pragma unroll
      for (int m = 0; m < 4; m++)
        af[m] = *(const short8*)&As[(wr * 64 + m * 16 + l15) * 64 + gp];
      #pragma unroll
      for (int n = 0; n < 4; n++)
        bf[n] = *(const short8*)&Bs[(wc * 64 + n * 16 + l15) * 64 + gp];
      #pragma unroll
      for (int m = 0; m < 4; m++)
        #pragma unroll
        for (int n = 0; n < 4; n++)
          acc[m][n] = __builtin_amdgcn_mfma_f32_16x16x32_bf16(af[m], bf[n], acc[m][n], 0, 0, 0);
    }
    __syncthreads();
  }

  int row0 = blkM + wr * 64;
  int col0 = blkN + wc * 64;
  #pragma unroll
  for (int m = 0; m < 4; m++) {
    #pragma unroll
    for (int n = 0; n < 4; n++) {
      int colb = col0 + n * 16 + l15;
      #pragma unroll
      for (int j = 0; j < 4; j++) {
        int row = row0 + m * 16 + l4 * 4 + j;
        float v = acc[m][n][j];
        if (m0) {
          int s = colb >> 10, hd = colb & 1023;
          v += bias[hd * 3 + s];
          if (s == 0) v *= 0.18033688011112042f;  // (1/8)*log2(e): softmax scale + exp2 base
          size_t idx = ((size_t)((row >> 11) * NHEADS + (hd >> 6)) * SEQ + (row & 2047)) * DEPTH + (hd & 63);
          (s == 0 ? Qb : Kb)[idx] = f2bf(v);
        } else {
          v += bias[row * 3 + 2];
          Vtb[((size_t)(bz * 1024 + row)) * SEQ + colb] = f2bf(v);
        }
      }
    }
  }
}

// ---------------- proj gemm (fp32 out): 128x64 tiles, BK=64 swizzled, XCD-mapped ----------------
__global__ __launch_bounds__(256, 3) void mha_gemm_proj(
    const unsigned short* __restrict__ A,
    const unsigned short* __restrict__ Bt,
    const float* __restrict__ bias,
    float* __restrict__ out_f)
{
  __shared__ __align__(16) unsigned short As[128 * 64];   // 16KB
  __shared__ __align__(16) unsigned short Bs[64 * 64];    // 8KB
  const int K = 1024;
  int id = blockIdx.x;                 // 512 blocks
  int xcd = id & 7, idx = id >> 3;
  int by = xcd * 4 + (idx >> 4);       // 0..31
  int bx = idx & 15;                   // 0..15 (64-col panels)
  int t = threadIdx.x;
  int wv = t >> 6, lane = t & 63;
  int l15 = lane & 15, l4 = lane >> 4;
  int wr = wv >> 1, wc = wv & 1;
  int blkM = by * 128, blkN = bx * 64;

  f32x4 acc[4][2];
  for (int m = 0; m < 4; m++) for (int n = 0; n < 2; n++) acc[m][n] = (f32x4){0.f,0.f,0.f,0.f};

  for (int kt = 0; kt < K; kt += 64) {
    #pragma unroll
    for (int i = 0; i < 4; i++) {
      int e = i * 256 + t;
      int row = e >> 3;
      int sc = ((e & 7) ^ (row & 7)) * 8;
      gload_lds16(A + (size_t)(blkM + row) * K + kt + sc, As + e * 8);
    }
    #pragma unroll
    for (int i = 0; i < 2; i++) {
      int e = i * 256 + t;
      int row = e >> 3;
      int sc = ((e & 7) ^ (row & 7)) * 8;
      gload_lds16(Bt + (size_t)(blkN + row) * K + kt + sc, Bs + e * 8);
    }
    __syncthreads();
    #pragma unroll
    for (int kk = 0; kk < 2; kk++) {
      int gp = ((kk * 4 + l4) ^ (l15 & 7)) * 8;
      short8 af[4], bf[2];
      #pragma unroll
      for (int m = 0; m < 4; m++)
        af[m] = *(const short8*)&As[(wr * 64 + m * 16 + l15) * 64 + gp];
      #pragma unroll
      for (int n = 0; n < 2; n++)
        bf[n] = *(const short8*)&Bs[(wc * 32 + n * 16 + l15) * 64 + gp];
      #pragma unroll
      for (int m = 0; m < 4; m++)
        #pragma unroll
        for (int n = 0; n < 2; n++)
          acc[m][n] = __builtin_amdgcn_mfma_f32_16x16x32_bf16(af[m], bf[n], acc[m][n], 0, 0, 0);
    }
    __syncthreads();
  }

  int row0 = blkM + wr * 64;
  int col0 = blkN + wc * 32;
  #pragma unroll
  for (int m = 0; m < 4; m++) {
    #pragma unroll
    for (int n = 0; n < 2; n++) {
      int colb = col0 + n * 16 + l15;
      #pragma unroll
      for (int j = 0; j < 4; j++) {
        int row = row0 + m * 16 + l4 * 4 + j;
        out_f[(size_t)row * D_MODEL + colb] = acc[m][n][j] + bias[colb];
      }
    }
  }
}

// -------- flash attention: KVBLK=128, two 32-key groups per wave per barrier section --------
// (best measured config: 45.2us ~ plain-HIP attn structure ceiling ~943 TF)
__global__ __launch_bounds__(512, 2) void mha_attn(
    const unsigned short* __restrict__ Q,
    const unsigned short* __restrict__ Kb,
    const unsigned short* __restrict__ Vt,
    unsigned short* __restrict__ O)
{
  const int N = SEQ;
  const int NIT = N / 128;                   // 16
  int id = blockIdx.x;                       // 512 blocks
  int bh    = (id & 7) * 4 + ((id >> 7) & 3);  // 4 heads per XCD
  int qtile = (id >> 3) & 15;                // 16 q-tiles of 128 rows
  int t = threadIdx.x, wv = t >> 6, lane = t & 63;
  int l31 = lane & 31, hi = lane >> 5;
  int kh = wv & 1, qh = wv >> 1;             // key-half (64 keys), q-group 0..3

  // 64KB: per buf {K[128][64] @0 | V[64][128] @8192 elems}; combine scratch overlaid after loop
  __shared__ __align__(16) unsigned short SMEM[2 * 16384];

  const unsigned short* Kbh = Kb + (size_t)bh * N * DEPTH;
  const unsigned short* Vbh = Vt + (size_t)bh * DEPTH * N;

  int qrow = qtile * 128 + qh * 32 + l31;
  const unsigned short* Qp = Q + ((size_t)bh * N + qrow) * DEPTH + hi * 8;
  short8 qf[4];
  #pragma unroll
  for (int c = 0; c < 4; c++) qf[c] = *(const short8*)(Qp + c * 16);

  // staging: thread t stages K granules {t, t+512} and V granules {t, t+512}
  int krow = t >> 3;                              // 0..63 (K rows 64..127 via +4096 elem offset)
  int ksc  = ((t & 7) ^ (krow & 7)) * 8;          // (krow+64)&7 == krow&7 -> same swizzle
  const unsigned short* kst = Kbh + (size_t)krow * DEPTH + ksc;
  int vrow = t >> 4;                              // 0..31 (V rows 32..63 via +32*N offset)
  int vg   = t & 15;
  int vsc  = ((vg ^ (vrow & 7))) * 8;             // (vrow+32)&7 == vrow&7
  const unsigned short* vst = Vbh + (size_t)vrow * N + vsc;

  // swizzled LDS reads: K tile row r (64-elem rows), V tile row r (128-elem rows)
  int rbK0 = (kh * 64 + l31) * 64;                // group0 key rows; group1: +2048
  int rbV0 = l31 * 128, rbV1 = rbV0 + 4096;       // V rows l31 / l31+32
  int goQK[4], goPV[4];
  #pragma unroll
  for (int c = 0; c < 4; c++) goQK[c] = ((c * 2 + hi) ^ (l31 & 7)) * 8;
  #pragma unroll
  for (int i = 0; i < 4; i++) {                   // i = g*2+lc
    int g = i >> 1, lc = i & 1;
    goPV[i] = ((kh * 8 + g * 4 + lc * 2 + hi) ^ (l31 & 7)) * 8;
  }

  short8 ones;
  #pragma unroll
  for (int i = 0; i < 8; i++) ones[i] = (short)0x3F80;   // bf16 1.0

  f32x16 o0, o1, lsacc, zc;
  #pragma unroll
  for (int i = 0; i < 16; i++) { o0[i] = 0.f; o1[i] = 0.f; lsacc[i] = 0.f; zc[i] = 0.f; }

  // prologue: stage tile 0 into buf 0 (4 gloads/thread)
  gload_lds16(kst,                       SMEM + t * 8);
  gload_lds16(kst + 4096,                SMEM + 4096 + t * 8);
  gload_lds16(vst,                       SMEM + 8192 + t * 8);
  gload_lds16(vst + (size_t)32 * N,      SMEM + 12288 + t * 8);
  asm volatile("s_waitcnt vmcnt(0)" ::: "memory");
  __builtin_amdgcn_sched_barrier(0);
  __builtin_amdgcn_s_barrier();
  __builtin_amdgcn_sched_barrier(0);

#define BODY(BUF, IT)                                                                     \
  do {                                                                                    \
    if ((IT) + 1 < NIT) {                                                                 \
      unsigned short* nb = SMEM + ((BUF) ^ 1) * 16384;                                    \
      const unsigned short* kn = kst + (size_t)((IT) + 1) * 8192;                         \
      const unsigned short* vn = vst + ((IT) + 1) * 128;                                  \
      gload_lds16(kn,                  nb + t * 8);                                       \
      gload_lds16(kn + 4096,           nb + 4096 + t * 8);                                \
      gload_lds16(vn,                  nb + 8192 + t * 8);                                \
      gload_lds16(vn + (size_t)32 * N, nb + 12288 + t * 8);                               \
    }                                                                                     \
    {                                                                                     \
      const unsigned short* Kc = SMEM + (BUF) * 16384;                                    \
      const unsigned short* Vc = Kc + 8192;                                               \
      _Pragma("unroll") for (int g = 0; g < 2; g++) {                                     \
        __builtin_amdgcn_s_setprio(1);                                                    \
        short8 ka0 = *(const short8*)&Kc[rbK0 + g * 2048 + goQK[0]];                      \
        f32x16 s = __builtin_amdgcn_mfma_f32_32x32x16_bf16(ka0, qf[0], zc, 0, 0, 0);      \
        _Pragma("unroll") for (int c = 1; c < 4; c++) {                                   \
          short8 ka = *(const short8*)&Kc[rbK0 + g * 2048 + goQK[c]];                     \
          s = __builtin_amdgcn_mfma_f32_32x32x16_bf16(ka, qf[c], s, 0, 0, 0);             \
        }                                                                                 \
        __builtin_amdgcn_s_setprio(0);                                                    \
        float p[16];                                                                      \
        _Pragma("unroll") for (int r = 0; r < 16; r++) p[r] = EXP2(s[r]);                 \
        _Pragma("unroll") for (int lc = 0; lc < 2; lc++) {                                \
          unsigned int X0 = cvt_pk_bf16(p[8*lc+0], p[8*lc+1]);                            \
          unsigned int X1 = cvt_pk_bf16(p[8*lc+2], p[8*lc+3]);                            \
          unsigned int X2 = cvt_pk_bf16(p[8*lc+4], p[8*lc+5]);                            \
          unsigned int X3 = cvt_pk_bf16(p[8*lc+6], p[8*lc+7]);                            \
          auto r02 = __builtin_amdgcn_permlane32_swap(X0, X2, false, false);              \
          auto r13 = __builtin_amdgcn_permlane32_swap(X1, X3, false, false);              \
          uint4v wvec; wvec[0] = r02[0]; wvec[1] = r13[0]; wvec[2] = r02[1]; wvec[3] = r13[1]; \
          short8 bfrag = __builtin_bit_cast(short8, wvec);                                \
          short8 va = *(const short8*)&Vc[rbV0 + goPV[g * 2 + lc]];                       \
          short8 vb = *(const short8*)&Vc[rbV1 + goPV[g * 2 + lc]];                       \
          __builtin_amdgcn_s_setprio(1);                                                  \
          o0 = __builtin_amdgcn_mfma_f32_32x32x16_bf16(va, bfrag, o0, 0, 0, 0);           \
          o1 = __builtin_amdgcn_mfma_f32_32x32x16_bf16(vb, bfrag, o1, 0, 0, 0);           \
          lsacc = __builtin_amdgcn_mfma_f32_32x32x16_bf16(ones, bfrag, lsacc, 0, 0, 0);   \
          __builtin_amdgcn_s_setprio(0);                                                  \
        }                                                                                 \
      }                                                                                   \
    }                                                                                     \
    if ((IT) + 1 < NIT) {                                                                 \
      asm volatile("s_waitcnt vmcnt(0)" ::: "memory");                                    \
      __builtin_amdgcn_sched_barrier(0);                                                  \
      __builtin_amdgcn_s_barrier();                                                       \
      __builtin_amdgcn_sched_barrier(0);                                                  \
    }                                                                                     \
  } while (0)

  for (int it2 = 0; it2 < NIT; it2 += 2) {
    BODY(0, it2);
    BODY(1, it2 + 1);
  }
#undef BODY

  float ls = lsacc[0];   // every acc reg = sum over this wave's key-half (all tiles)

  // ---- combine key-split partials (kh 0/1) via scratch overlaid on SMEM (loop done) ----
  __syncthreads();                                 // everyone done reading K/V tiles
  float* cmb = (float*)SMEM;                       // 4 slots x 64 x 33 = 33.8KB <= 64KB
  if (kh == 1) {
    float* c0 = cmb + (qh * 64 + lane) * 33;
    #pragma unroll
    for (int i = 0; i < 16; i++) { c0[i] = o0[i]; c0[16 + i] = o1[i]; }
    c0[32] = ls;
  }
  __syncthreads();
  if (kh == 0) {
    const float* c0 = cmb + (qh * 64 + lane) * 33;
    #pragma unroll
    for (int i = 0; i < 16; i++) { o0[i] += c0[i]; o1[i] += c0[16 + i]; }
    float rl = 1.0f / (ls + c0[32]);

    int b = bh >> 4, h = bh & 15;
    unsigned short* Op = O + ((size_t)b * N + qrow) * D_MODEL + h * DEPTH;
    // acc layout: col q = l31, row d = (reg&3) + 8*(reg>>2) + 4*hi (+32 for o1)
    #pragma unroll
    for (int gq = 0; gq < 4; gq++) {
      #pragma unroll
      for (int rp = 0; rp < 2; rp++) {
        int reg = gq * 4 + rp * 2;
        int d = gq * 8 + hi * 4 + rp * 2;
        *(unsigned int*)(Op + d)      = cvt_pk_bf16(o0[reg] * rl, o0[reg + 1] * rl);
        *(unsigned int*)(Op + 32 + d) = cvt_pk_bf16(o1[reg] * rl, o1[reg + 1] * rl);
      }
    }
  }
}

extern "C" void kernel_launch(void* const* d_in, const int* in_sizes, int n_in,
                              void* d_out, int out_size, void* d_ws, size_t ws_size,
                              hipStream_t stream) {
  const float* x     = (const float*)d_in[0];
  const float* Wqkv  = (const float*)d_in[1];
  const float* bqkv  = (const float*)d_in[2];
  const float* Wproj = (const float*)d_in[3];
  const float* bproj = (const float*)d_in[4];
  float* out = (float*)d_out;

  char* w = (char*)d_ws;
  unsigned short* xb    = (unsigned short*)(w);                       // 8 MB
  unsigned short* wqkT  = (unsigned short*)(w + 8388608);             // 4 MB
  unsigned short* wvT   = (unsigned short*)(w + 8388608 + 4194304);   // 2 MB
  unsigned short* wpT   = (unsigned short*)(w + 8388608 + 4194304 + 2097152);  // 2 MB
  unsigned short* Qbuf  = (unsigned short*)(w + 16777216);            // 8 MB
  unsigned short* Kbuf  = (unsigned short*)(w + 16777216 + 8388608);  // 8 MB
  unsigned short* Vtb   = (unsigned short*)(w + 16777216 + 16777216); // 8 MB
  unsigned short* AOut  = (unsigned short*)(w + 16777216 + 25165824); // 8 MB

  // 1. merged prep (x cvt + Wqkv permute + Wproj transpose)
  mha_prep<<<6144, 256, 0, stream>>>(x, Wqkv, Wproj, xb, wqkT, wvT, wpT);
  // 2. merged QKV gemm (QK: 512 blocks XCD-mapped, V: 256 blocks), BK=64, 1-phase 3 blk/CU
  mha_gemm_qkv<<<768, 256, 0, stream>>>(xb, wqkT, wvT, bqkv, Qbuf, Kbuf, Vtb);
  // 3. flash attention (512 blocks x 512 thr, KVBLK=128, 2 blocks/CU)
  mha_attn<<<512, 512, 0, stream>>>(Qbuf, Kbuf, Vtb, AOut);
  // 4. projection gemm 128x64 tiles, BK=64, XCD-mapped -> fp32 out
  mha_gemm_proj<<<512, 256, 0, stream>>>(AOut, wpT, bproj, out);
}